// Round 2
// baseline (170.794 us; speedup 1.0000x reference)
//
#include <hip/hip_runtime.h>
#include <hip/hip_bf16.h>

#define N_SRC   131072
#define N_DST   65536
#define D       128      // D_IN == D_OUT == 128

typedef __bf16 bf16x8 __attribute__((ext_vector_type(8)));
typedef float  f32x4  __attribute__((ext_vector_type(4)));

#define CONV_BLOCKS 8192   // (N_SRC*D) / (256 threads * 8 elems) = 8192
#define W_BLOCKS    64     // 64*256 = 16384 = D*D elements

// ---------------------------------------------------------------------------
// Kernel 1 (fused prep): role-split grid.
//  blocks [0, CONV_BLOCKS)                : feat fp32 -> bf16 (streaming)
//  blocks [CONV_BLOCKS, CONV+n_bnd)       : sorted dst -> CSR row_start
//  blocks [CONV+n_bnd, CONV+n_bnd+64)     : W fp32 [k][n] -> Wt bf16 [n][k]
// ---------------------------------------------------------------------------
__global__ __launch_bounds__(256) void prep_kernel(
    const float* __restrict__ feat,
    const int*   __restrict__ dst, int n_edges, int n_bnd_blocks,
    const float* __restrict__ W_self, const float* __restrict__ W_neigh,
    __bf16* __restrict__ feat_bf,
    int*    __restrict__ row_start,
    __bf16* __restrict__ Wt_self, __bf16* __restrict__ Wt_neigh)
{
    const int b = blockIdx.x;
    const int t = threadIdx.x;

    if (b < CONV_BLOCKS) {
        const size_t i0 = ((size_t)b * 256 + t) * 8;
        const float4 a0 = *(const float4*)&feat[i0];
        const float4 a1 = *(const float4*)&feat[i0 + 4];
        bf16x8 o;
        o[0] = (__bf16)a0.x; o[1] = (__bf16)a0.y; o[2] = (__bf16)a0.z; o[3] = (__bf16)a0.w;
        o[4] = (__bf16)a1.x; o[5] = (__bf16)a1.y; o[6] = (__bf16)a1.z; o[7] = (__bf16)a1.w;
        *(bf16x8*)&feat_bf[i0] = o;
    } else if (b < CONV_BLOCKS + n_bnd_blocks) {
        const int e = (b - CONV_BLOCKS) * 256 + t;
        if (e < n_edges) {
            const int d    = dst[e];
            const int prev = (e == 0) ? -1 : dst[e - 1];
            for (int r = prev + 1; r <= d; ++r) row_start[r] = e;
            if (e == n_edges - 1)
                for (int r = d + 1; r <= N_DST; ++r) row_start[r] = n_edges;
        }
    } else {
        const int wb  = b - CONV_BLOCKS - n_bnd_blocks;  // 0..63
        const int idx = wb * 256 + t;                    // 0..16383
        const int k = idx >> 7, n = idx & 127;
        Wt_self [n * D + k] = (__bf16)W_self [k * D + n];
        Wt_neigh[n * D + k] = (__bf16)W_neigh[k * D + n];
    }
}

// ---------------------------------------------------------------------------
// Kernel 2 (fused neigh + dual GEMM).
// Round-2 change: MTILE 128->64, grid 512->1024 (4 blocks/CU), MREP 2->1.
// Rationale (rocprof r1): Occupancy 18.5%, MfmaUtil 3%, VALUBusy 21%,
// HBM 26% -> latency-bound gather with only 2 blocks/CU. Smaller tile gives
// 4 blocks/CU (16 waves/CU at <=128 VGPR, enforced by __launch_bounds__),
// halves each group's serial row chain (8 rows -> 4), and smooths degree
// imbalance. Self-path A-fragments are prefetched to registers BEFORE the
// gather so their global latency hides under it.
//
// Phase 1: gather-mean. 16 groups x 16 lanes; group g handles rows
//   {g, g+16, g+32, g+48}. Predicated unroll-8 edge loop (8 independent
//   16 B gathers in flight, mask-FMA). Stored to LDS with XOR swizzle
//   byte ^= (row&7)<<4 (conflict-free ds_read_b128 in phase 2; verified
//   r1: SQ_LDS_BANK_CONFLICT ~0).
//
// Phase 2: self-path GEMM (register A, no LDS dep -> before barrier,
//   absorbs gather imbalance), barrier, neigh-path GEMM from LDS.
//   MFMA bf16 16x16x32 layouts (HW-verified prior rounds):
//     A: lane holds A[m = lane&15][k = (lane>>4)*8 + j]
//     B: lane holds B[k = (lane>>4)*8 + j][n = lane&15]   (from Wt[n][k])
//     C/D: col = lane&15, row = (lane>>4)*4 + reg
// ---------------------------------------------------------------------------
#define MTILE 64

__global__ __launch_bounds__(256, 4) void fused_kernel(
    const __bf16* __restrict__ feat_bf,   // bf16 N_SRC x D
    const int*    __restrict__ src,
    const int*    __restrict__ row_start,
    const __bf16* __restrict__ Wt_self,   // bf16 [n][k]
    const __bf16* __restrict__ Wt_neigh,  // bf16 [n][k]
    const float*  __restrict__ b_self,
    const float*  __restrict__ b_neigh,
    float*        __restrict__ out)
{
    __shared__ __align__(16) __bf16 hs[MTILE * D];   // 16 KB, XOR-swizzled rows
    char* hsb = (char*)hs;

    const int t     = threadIdx.x;
    const int tile0 = blockIdx.x * MTILE;

    // GEMM lane ids (also used for the self-A prefetch)
    const int w    = t >> 6;          // wave 0..3
    const int l    = t & 63;
    const int m16  = l & 15;
    const int quad = l >> 4;          // 0..3
    const int kb   = quad * 8;
    const int rowloc0 = w * 16;       // wave's first tile-local row
    const int rowbase = tile0 + rowloc0;

    // prefetch self-path A fragments (issued before gather; latency hidden)
    bf16x8 aself[4];
    #pragma unroll
    for (int ks = 0; ks < 4; ++ks)
        aself[ks] = *(const bf16x8*)&feat_bf[(size_t)(rowbase + m16) * D + ks * 32 + kb];

    // ---------------- phase 1: gather-mean into LDS ----------------
    {
        const int g    = t >> 4;       // group 0..15
        const int lane = t & 15;
        const int cb   = lane * 16;    // byte offset of this lane's 16B chunk

        #pragma unroll
        for (int rr = 0; rr < MTILE / 16; ++rr) {
            const int rloc = rr * 16 + g;
            const int s0 = row_start[tile0 + rloc];
            const int s1 = row_start[tile0 + rloc + 1];

            float acc[8] = {0.f, 0.f, 0.f, 0.f, 0.f, 0.f, 0.f, 0.f};

            for (int base = s0; base < s1; base += 8) {
                int idx[8];
                #pragma unroll
                for (int j = 0; j < 8; ++j) {
                    const int e = base + j;
                    idx[j] = src[e < s1 ? e : s1 - 1];
                }
                bf16x8 v[8];
                #pragma unroll
                for (int j = 0; j < 8; ++j)
                    v[j] = *(const bf16x8*)((const char*)feat_bf + (size_t)idx[j] * (D * 2) + cb);
                #pragma unroll
                for (int j = 0; j < 8; ++j) {
                    const float m = (base + j < s1) ? 1.0f : 0.0f;
                    #pragma unroll
                    for (int c = 0; c < 8; ++c)
                        acc[c] = fmaf(m, (float)v[j][c], acc[c]);
                }
            }

            const float inv = 1.0f / fmaxf((float)(s1 - s0), 1.0f);
            bf16x8 o;
            #pragma unroll
            for (int c = 0; c < 8; ++c) o[c] = (__bf16)(acc[c] * inv);
            // swizzled LDS store (row stride 256 B, chunk XOR by row&7)
            *(bf16x8*)(hsb + rloc * 256 + (cb ^ ((rloc & 7) << 4))) = o;
        }
    }

    // ---------------- phase 2: dual GEMM ----------------
    f32x4 acc[8];
    #pragma unroll
    for (int nb = 0; nb < 8; ++nb)
        acc[nb] = (f32x4){0.f, 0.f, 0.f, 0.f};

    // self path: A from prefetched registers (no LDS dep -> before barrier)
    #pragma unroll
    for (int ks = 0; ks < 4; ++ks) {
        #pragma unroll
        for (int nb = 0; nb < 8; ++nb) {
            const bf16x8 bfrag = *(const bf16x8*)&Wt_self[(size_t)(nb * 16 + m16) * D + ks * 32 + kb];
            acc[nb] = __builtin_amdgcn_mfma_f32_16x16x32_bf16(
                aself[ks], bfrag, acc[nb], 0, 0, 0);
        }
    }

    __syncthreads();

    // neigh path: A from swizzled LDS tile
    #pragma unroll
    for (int ks = 0; ks < 4; ++ks) {
        const int rloc  = rowloc0 + m16;
        const int cbyte = (ks * 32 + kb) * 2;
        const bf16x8 afrag = *(const bf16x8*)(hsb + rloc * 256 + (cbyte ^ ((rloc & 7) << 4)));
        #pragma unroll
        for (int nb = 0; nb < 8; ++nb) {
            const bf16x8 bfrag = *(const bf16x8*)&Wt_neigh[(size_t)(nb * 16 + m16) * D + ks * 32 + kb];
            acc[nb] = __builtin_amdgcn_mfma_f32_16x16x32_bf16(
                afrag, bfrag, acc[nb], 0, 0, 0);
        }
    }

    // epilogue
    #pragma unroll
    for (int nb = 0; nb < 8; ++nb) {
        const int col  = nb * 16 + m16;
        const float bias = b_self[col] + b_neigh[col];
        const int orow0 = rowbase + quad * 4;
        #pragma unroll
        for (int r = 0; r < 4; ++r)
            out[(size_t)(orow0 + r) * D + col] = acc[nb][r] + bias;
    }
}

// ---------------------------------------------------------------------------
extern "C" void kernel_launch(void* const* d_in, const int* in_sizes, int n_in,
                              void* d_out, int out_size, void* d_ws, size_t ws_size,
                              hipStream_t stream)
{
    const float* feat    = (const float*)d_in[0];
    const float* W_self  = (const float*)d_in[1];
    const float* b_self  = (const float*)d_in[2];
    const float* W_neigh = (const float*)d_in[3];
    const float* b_neigh = (const float*)d_in[4];
    const int*   src_idx = (const int*)d_in[5];
    const int*   dst_idx = (const int*)d_in[6];
    const int n_edges = in_sizes[5];

    // workspace layout
    char* ws = (char*)d_ws;
    __bf16* feat_bf  = (__bf16*)ws;                                  // 32 MB
    int*    row_start = (int*)(feat_bf + (size_t)N_SRC * D);         // 256 KB
    __bf16* Wt_self  = (__bf16*)(row_start + N_DST + 16);
    __bf16* Wt_neigh = Wt_self + D * D;

    const int n_bnd = (n_edges + 255) / 256;
    prep_kernel<<<CONV_BLOCKS + n_bnd + W_BLOCKS, 256, 0, stream>>>(
        feat, dst_idx, n_edges, n_bnd, W_self, W_neigh,
        feat_bf, row_start, Wt_self, Wt_neigh);

    fused_kernel<<<N_DST / MTILE, 256, 0, stream>>>(
        feat_bf, src_idx, row_start, Wt_self, Wt_neigh,
        b_self, b_neigh, (float*)d_out);
}

// Round 3
// 170.511 us; speedup vs baseline: 1.0017x; 1.0017x over previous
//
#include <hip/hip_runtime.h>
#include <hip/hip_bf16.h>

#define N_SRC   131072
#define N_DST   65536
#define D       128      // D_IN == D_OUT == 128

typedef __bf16 bf16x8 __attribute__((ext_vector_type(8)));
typedef float  f32x4  __attribute__((ext_vector_type(4)));

#define CONV_BLOCKS 8192   // (N_SRC*D) / (256 threads * 8 elems) = 8192
#define W_BLOCKS    64     // 64*256 = 16384 = D*D elements

// ---------------------------------------------------------------------------
// Kernel 1 (fused prep): role-split grid.
//  blocks [0, CONV_BLOCKS)                : feat fp32 -> bf16 (streaming)
//  blocks [CONV_BLOCKS, CONV+n_bnd)       : sorted dst -> CSR row_start
//  blocks [CONV+n_bnd, CONV+n_bnd+64)     : W fp32 [k][n] -> Wt bf16 [n][k]
// ---------------------------------------------------------------------------
__global__ __launch_bounds__(256) void prep_kernel(
    const float* __restrict__ feat,
    const int*   __restrict__ dst, int n_edges, int n_bnd_blocks,
    const float* __restrict__ W_self, const float* __restrict__ W_neigh,
    __bf16* __restrict__ feat_bf,
    int*    __restrict__ row_start,
    __bf16* __restrict__ Wt_self, __bf16* __restrict__ Wt_neigh)
{
    const int b = blockIdx.x;
    const int t = threadIdx.x;

    if (b < CONV_BLOCKS) {
        const size_t i0 = ((size_t)b * 256 + t) * 8;
        const float4 a0 = *(const float4*)&feat[i0];
        const float4 a1 = *(const float4*)&feat[i0 + 4];
        bf16x8 o;
        o[0] = (__bf16)a0.x; o[1] = (__bf16)a0.y; o[2] = (__bf16)a0.z; o[3] = (__bf16)a0.w;
        o[4] = (__bf16)a1.x; o[5] = (__bf16)a1.y; o[6] = (__bf16)a1.z; o[7] = (__bf16)a1.w;
        *(bf16x8*)&feat_bf[i0] = o;
    } else if (b < CONV_BLOCKS + n_bnd_blocks) {
        const int e = (b - CONV_BLOCKS) * 256 + t;
        if (e < n_edges) {
            const int d    = dst[e];
            const int prev = (e == 0) ? -1 : dst[e - 1];
            for (int r = prev + 1; r <= d; ++r) row_start[r] = e;
            if (e == n_edges - 1)
                for (int r = d + 1; r <= N_DST; ++r) row_start[r] = n_edges;
        }
    } else {
        const int wb  = b - CONV_BLOCKS - n_bnd_blocks;  // 0..63
        const int idx = wb * 256 + t;                    // 0..16383
        const int k = idx >> 7, n = idx & 127;
        Wt_self [n * D + k] = (__bf16)W_self [k * D + n];
        Wt_neigh[n * D + k] = (__bf16)W_neigh[k * D + n];
    }
}

// ---------------------------------------------------------------------------
// Kernel 2 (fused neigh + dual GEMM). MTILE=64, grid=1024 (4 blocks/CU).
//
// Round-3 changes vs round 2 (which regressed 48.4 -> 59.6 us):
//  * r2's __launch_bounds__(256,4) made the allocator squeeze VGPR 108->64,
//    serializing the 8-deep gather pipeline (VALUBusy 21->17%). Now plain
//    __launch_bounds__(256): target ~115 VGPR (<=128 keeps 4 waves/SIMD).
//  * aself register prefetch removed (16 live VGPRs across the gather).
//  * Gather processes TWO rows per 16-lane group concurrently: 16
//    independent 16 B loads in flight per group; row B's src-index load
//    latency hides under row A's gather+FMA and vice versa.
//
// Phase 1: gather-mean. group g owns rows {g, g+16, g+32, g+48}; pipelined
//   pairs (g,g+16), (g+32,g+48). Predicated unroll-8 per row, mask-FMA,
//   indices clamped to [0, s1-1] (safe for empty rows). LDS store XOR-swizzle
//   byte ^= (row&7)<<4 -> conflict-free ds_read_b128 (verified r1/r2:
//   SQ_LDS_BANK_CONFLICT ~65K, negligible).
//
// Phase 2: self-path GEMM from global (no LDS dep, placed before the
//   barrier to absorb gather imbalance), barrier, neigh-path GEMM from LDS.
//   MFMA bf16 16x16x32 layouts (HW-verified):
//     A: lane holds A[m = lane&15][k = (lane>>4)*8 + j]
//     B: lane holds B[k = (lane>>4)*8 + j][n = lane&15]   (from Wt[n][k])
//     C/D: col = lane&15, row = (lane>>4)*4 + reg
// ---------------------------------------------------------------------------
#define MTILE 64

__global__ __launch_bounds__(256) void fused_kernel(
    const __bf16* __restrict__ feat_bf,   // bf16 N_SRC x D
    const int*    __restrict__ src,
    const int*    __restrict__ row_start,
    const __bf16* __restrict__ Wt_self,   // bf16 [n][k]
    const __bf16* __restrict__ Wt_neigh,  // bf16 [n][k]
    const float*  __restrict__ b_self,
    const float*  __restrict__ b_neigh,
    float*        __restrict__ out)
{
    __shared__ __align__(16) __bf16 hs[MTILE * D];   // 16 KB, XOR-swizzled rows
    char* hsb = (char*)hs;

    const int t     = threadIdx.x;
    const int tile0 = blockIdx.x * MTILE;

    // ---------------- phase 1: gather-mean into LDS (2-row pipeline) -------
    {
        const int g    = t >> 4;       // group 0..15
        const int lane = t & 15;
        const int cb   = lane * 16;    // byte offset of this lane's 16B chunk

        #pragma unroll
        for (int pp = 0; pp < 2; ++pp) {
            const int rA  = pp * 32 + g;
            const int rB  = rA + 16;
            const int sA0 = row_start[tile0 + rA];
            const int sA1 = row_start[tile0 + rA + 1];
            const int sB0 = row_start[tile0 + rB];
            const int sB1 = row_start[tile0 + rB + 1];

            float accA[8] = {0.f,0.f,0.f,0.f,0.f,0.f,0.f,0.f};
            float accB[8] = {0.f,0.f,0.f,0.f,0.f,0.f,0.f,0.f};

            const int nA  = (sA1 - sA0 + 7) >> 3;
            const int nB  = (sB1 - sB0 + 7) >> 3;
            const int nIt = nA > nB ? nA : nB;

            int baseA = sA0, baseB = sB0;
            for (int it = 0; it < nIt; ++it, baseA += 8, baseB += 8) {
                int idxA[8], idxB[8];
                #pragma unroll
                for (int j = 0; j < 8; ++j) {
                    int eA = baseA + j; eA = eA < sA1 ? eA : sA1 - 1; eA = eA > 0 ? eA : 0;
                    idxA[j] = src[eA];
                }
                #pragma unroll
                for (int j = 0; j < 8; ++j) {
                    int eB = baseB + j; eB = eB < sB1 ? eB : sB1 - 1; eB = eB > 0 ? eB : 0;
                    idxB[j] = src[eB];
                }
                bf16x8 vA[8], vB[8];
                #pragma unroll
                for (int j = 0; j < 8; ++j)
                    vA[j] = *(const bf16x8*)((const char*)feat_bf + (size_t)idxA[j] * (D * 2) + cb);
                #pragma unroll
                for (int j = 0; j < 8; ++j)
                    vB[j] = *(const bf16x8*)((const char*)feat_bf + (size_t)idxB[j] * (D * 2) + cb);
                #pragma unroll
                for (int j = 0; j < 8; ++j) {
                    const float mA = (baseA + j < sA1) ? 1.0f : 0.0f;
                    #pragma unroll
                    for (int c = 0; c < 8; ++c)
                        accA[c] = fmaf(mA, (float)vA[j][c], accA[c]);
                }
                #pragma unroll
                for (int j = 0; j < 8; ++j) {
                    const float mB = (baseB + j < sB1) ? 1.0f : 0.0f;
                    #pragma unroll
                    for (int c = 0; c < 8; ++c)
                        accB[c] = fmaf(mB, (float)vB[j][c], accB[c]);
                }
            }

            const float invA = 1.0f / fmaxf((float)(sA1 - sA0), 1.0f);
            const float invB = 1.0f / fmaxf((float)(sB1 - sB0), 1.0f);
            bf16x8 oA, oB;
            #pragma unroll
            for (int c = 0; c < 8; ++c) oA[c] = (__bf16)(accA[c] * invA);
            #pragma unroll
            for (int c = 0; c < 8; ++c) oB[c] = (__bf16)(accB[c] * invB);
            *(bf16x8*)(hsb + rA * 256 + (cb ^ ((rA & 7) << 4))) = oA;
            *(bf16x8*)(hsb + rB * 256 + (cb ^ ((rB & 7) << 4))) = oB;
        }
    }

    // ---------------- phase 2: dual GEMM ----------------
    const int w    = t >> 6;          // wave 0..3
    const int l    = t & 63;
    const int m16  = l & 15;
    const int quad = l >> 4;          // 0..3
    const int kb   = quad * 8;
    const int rowloc0 = w * 16;       // wave's first tile-local row
    const int rowbase = tile0 + rowloc0;

    f32x4 acc[8];
    #pragma unroll
    for (int nb = 0; nb < 8; ++nb)
        acc[nb] = (f32x4){0.f, 0.f, 0.f, 0.f};

    // self path: A from global (no LDS dep -> before barrier)
    #pragma unroll
    for (int ks = 0; ks < 4; ++ks) {
        const bf16x8 afrag = *(const bf16x8*)&feat_bf[(size_t)(rowbase + m16) * D + ks * 32 + kb];
        #pragma unroll
        for (int nb = 0; nb < 8; ++nb) {
            const bf16x8 bfrag = *(const bf16x8*)&Wt_self[(size_t)(nb * 16 + m16) * D + ks * 32 + kb];
            acc[nb] = __builtin_amdgcn_mfma_f32_16x16x32_bf16(
                afrag, bfrag, acc[nb], 0, 0, 0);
        }
    }

    __syncthreads();

    // neigh path: A from swizzled LDS tile
    #pragma unroll
    for (int ks = 0; ks < 4; ++ks) {
        const int rloc  = rowloc0 + m16;
        const int cbyte = (ks * 32 + kb) * 2;
        const bf16x8 afrag = *(const bf16x8*)(hsb + rloc * 256 + (cbyte ^ ((rloc & 7) << 4)));
        #pragma unroll
        for (int nb = 0; nb < 8; ++nb) {
            const bf16x8 bfrag = *(const bf16x8*)&Wt_neigh[(size_t)(nb * 16 + m16) * D + ks * 32 + kb];
            acc[nb] = __builtin_amdgcn_mfma_f32_16x16x32_bf16(
                afrag, bfrag, acc[nb], 0, 0, 0);
        }
    }

    // epilogue
    #pragma unroll
    for (int nb = 0; nb < 8; ++nb) {
        const int col  = nb * 16 + m16;
        const float bias = b_self[col] + b_neigh[col];
        const int orow0 = rowbase + quad * 4;
        #pragma unroll
        for (int r = 0; r < 4; ++r)
            out[(size_t)(orow0 + r) * D + col] = acc[nb][r] + bias;
    }
}

// ---------------------------------------------------------------------------
extern "C" void kernel_launch(void* const* d_in, const int* in_sizes, int n_in,
                              void* d_out, int out_size, void* d_ws, size_t ws_size,
                              hipStream_t stream)
{
    const float* feat    = (const float*)d_in[0];
    const float* W_self  = (const float*)d_in[1];
    const float* b_self  = (const float*)d_in[2];
    const float* W_neigh = (const float*)d_in[3];
    const float* b_neigh = (const float*)d_in[4];
    const int*   src_idx = (const int*)d_in[5];
    const int*   dst_idx = (const int*)d_in[6];
    const int n_edges = in_sizes[5];

    // workspace layout
    char* ws = (char*)d_ws;
    __bf16* feat_bf  = (__bf16*)ws;                                  // 32 MB
    int*    row_start = (int*)(feat_bf + (size_t)N_SRC * D);         // 256 KB
    __bf16* Wt_self  = (__bf16*)(row_start + N_DST + 16);
    __bf16* Wt_neigh = Wt_self + D * D;

    const int n_bnd = (n_edges + 255) / 256;
    prep_kernel<<<CONV_BLOCKS + n_bnd + W_BLOCKS, 256, 0, stream>>>(
        feat, dst_idx, n_edges, n_bnd, W_self, W_neigh,
        feat_bf, row_start, Wt_self, Wt_neigh);

    fused_kernel<<<N_DST / MTILE, 256, 0, stream>>>(
        feat_bf, src_idx, row_start, Wt_self, Wt_neigh,
        b_self, b_neigh, (float*)d_out);
}

// Round 4
// 158.101 us; speedup vs baseline: 1.0803x; 1.0785x over previous
//
#include <hip/hip_runtime.h>
#include <hip/hip_bf16.h>

#define N_SRC   131072
#define N_DST   65536
#define D       128      // D_IN == D_OUT == 128

typedef __bf16 bf16x8 __attribute__((ext_vector_type(8)));
typedef float  f32x4  __attribute__((ext_vector_type(4)));

#define CONV_BLOCKS 8192   // (N_SRC*D) / (256 threads * 8 elems) = 8192
#define W_BLOCKS    64     // 64*256 = 16384 = D*D elements

// ---------------------------------------------------------------------------
// Kernel 1 (fused prep): role-split grid.
//  blocks [0, CONV_BLOCKS)                : feat fp32 -> bf16 (streaming)
//  blocks [CONV_BLOCKS, CONV+n_bnd)       : sorted dst -> CSR row_start
//  blocks [CONV+n_bnd, CONV+n_bnd+64)     : W fp32 [k][n] -> Wt bf16 [n][k]
// ---------------------------------------------------------------------------
__global__ __launch_bounds__(256) void prep_kernel(
    const float* __restrict__ feat,
    const int*   __restrict__ dst, int n_edges, int n_bnd_blocks,
    const float* __restrict__ W_self, const float* __restrict__ W_neigh,
    __bf16* __restrict__ feat_bf,
    int*    __restrict__ row_start,
    __bf16* __restrict__ Wt_self, __bf16* __restrict__ Wt_neigh)
{
    const int b = blockIdx.x;
    const int t = threadIdx.x;

    if (b < CONV_BLOCKS) {
        const size_t i0 = ((size_t)b * 256 + t) * 8;
        const float4 a0 = *(const float4*)&feat[i0];
        const float4 a1 = *(const float4*)&feat[i0 + 4];
        bf16x8 o;
        o[0] = (__bf16)a0.x; o[1] = (__bf16)a0.y; o[2] = (__bf16)a0.z; o[3] = (__bf16)a0.w;
        o[4] = (__bf16)a1.x; o[5] = (__bf16)a1.y; o[6] = (__bf16)a1.z; o[7] = (__bf16)a1.w;
        *(bf16x8*)&feat_bf[i0] = o;
    } else if (b < CONV_BLOCKS + n_bnd_blocks) {
        const int e = (b - CONV_BLOCKS) * 256 + t;
        if (e < n_edges) {
            const int d    = dst[e];
            const int prev = (e == 0) ? -1 : dst[e - 1];
            for (int r = prev + 1; r <= d; ++r) row_start[r] = e;
            if (e == n_edges - 1)
                for (int r = d + 1; r <= N_DST; ++r) row_start[r] = n_edges;
        }
    } else {
        const int wb  = b - CONV_BLOCKS - n_bnd_blocks;  // 0..63
        const int idx = wb * 256 + t;                    // 0..16383
        const int k = idx >> 7, n = idx & 127;
        Wt_self [n * D + k] = (__bf16)W_self [k * D + n];
        Wt_neigh[n * D + k] = (__bf16)W_neigh[k * D + n];
    }
}

// ---------------------------------------------------------------------------
// Kernel 2 (fused neigh + dual GEMM).
// Round-4 structure: 512-thread blocks, MTILE=128, grid=512 (2 blocks/CU).
//  * Gather TLP doubled vs r1 (16 waves/CU vs 8) WITHOUT changing the
//    per-wave gather code (r1's verified loop, no clamp-padding, no
//    wasted loads). 32 groups/block -> each group owns 4 rows (serial
//    row chain halved vs r1's 8).
//  * row_start[129] staged in LDS at block start: removes 2 dependent
//    L2 round-trips from every row's critical path.
//  * GEMM: waves 0-3 run r1's exact MREP=2 shape (B-frag reuse x2,
//    proven best); waves 4-7 only gather, then wait at the barrier and
//    exit. GEMM-active waves/CU = 8, same as r1.
// Phase order: gather (all 8 waves) -> self-GEMM from global (waves 0-3,
// no LDS dep, absorbs gather imbalance) -> barrier -> neigh-GEMM from
// swizzled LDS (waves 0-3) -> epilogue.
// LDS: 32 KB tile + 0.6 KB rs; XOR swizzle byte^=(row&7)<<4 keeps
// ds_read_b128 conflict-free (verified r1-r3: SQ_LDS_BANK_CONFLICT ~65K).
// MFMA bf16 16x16x32 layouts (HW-verified):
//   A: lane holds A[m = lane&15][k = (lane>>4)*8 + j]
//   B: lane holds B[k = (lane>>4)*8 + j][n = lane&15]   (from Wt[n][k])
//   C/D: col = lane&15, row = (lane>>4)*4 + reg
// ---------------------------------------------------------------------------
#define MTILE 128
#define MREP  2

__global__ __launch_bounds__(512) void fused_kernel(
    const __bf16* __restrict__ feat_bf,   // bf16 N_SRC x D
    const int*    __restrict__ src,
    const int*    __restrict__ row_start,
    const __bf16* __restrict__ Wt_self,   // bf16 [n][k]
    const __bf16* __restrict__ Wt_neigh,  // bf16 [n][k]
    const float*  __restrict__ b_self,
    const float*  __restrict__ b_neigh,
    float*        __restrict__ out)
{
    __shared__ __align__(16) __bf16 hs[MTILE * D];   // 32 KB, XOR-swizzled rows
    __shared__ int rs[MTILE + 1];
    char* hsb = (char*)hs;

    const int t     = threadIdx.x;
    const int tile0 = blockIdx.x * MTILE;

    // stage CSR bounds for this tile (1 coalesced load, kills per-row trips)
    if (t <= MTILE) rs[t] = row_start[tile0 + t];
    __syncthreads();

    // ---------------- phase 1: gather-mean into LDS ----------------
    {
        const int g    = t >> 4;       // group 0..31
        const int lane = t & 15;
        const int cb   = lane * 16;    // byte offset of this lane's 16B chunk

        #pragma unroll
        for (int rr = 0; rr < MTILE / 32; ++rr) {   // 4 rows per group
            const int rloc = rr * 32 + g;
            const int s0 = rs[rloc];
            const int s1 = rs[rloc + 1];

            float acc[8] = {0.f, 0.f, 0.f, 0.f, 0.f, 0.f, 0.f, 0.f};

            for (int base = s0; base < s1; base += 8) {
                int idx[8];
                #pragma unroll
                for (int j = 0; j < 8; ++j) {
                    const int e = base + j;
                    idx[j] = src[e < s1 ? e : s1 - 1];
                }
                bf16x8 v[8];
                #pragma unroll
                for (int j = 0; j < 8; ++j)
                    v[j] = *(const bf16x8*)((const char*)feat_bf + (size_t)idx[j] * (D * 2) + cb);
                #pragma unroll
                for (int j = 0; j < 8; ++j) {
                    const float m = (base + j < s1) ? 1.0f : 0.0f;
                    #pragma unroll
                    for (int c = 0; c < 8; ++c)
                        acc[c] = fmaf(m, (float)v[j][c], acc[c]);
                }
            }

            const float inv = 1.0f / fmaxf((float)(s1 - s0), 1.0f);
            bf16x8 o;
            #pragma unroll
            for (int c = 0; c < 8; ++c) o[c] = (__bf16)(acc[c] * inv);
            // swizzled LDS store (row stride 256 B, chunk XOR by row&7)
            *(bf16x8*)(hsb + rloc * 256 + (cb ^ ((rloc & 7) << 4))) = o;
        }
    }

    // ---------------- phase 2: dual GEMM (waves 0-3 only) ----------------
    const int w    = t >> 6;          // wave 0..7
    const int l    = t & 63;
    const int m16  = l & 15;
    const int quad = l >> 4;          // 0..3
    const int kb   = quad * 8;
    const int rowloc0 = w * (16 * MREP);     // wave's first tile-local row
    const int rowbase = tile0 + rowloc0;

    f32x4 acc[MREP][8];
    if (w < 4) {
        #pragma unroll
        for (int rp = 0; rp < MREP; ++rp)
            #pragma unroll
            for (int nb = 0; nb < 8; ++nb)
                acc[rp][nb] = (f32x4){0.f, 0.f, 0.f, 0.f};

        // self path: A straight from global bf16 (no LDS dep -> before barrier)
        #pragma unroll
        for (int ks = 0; ks < 4; ++ks) {
            bf16x8 afrag[MREP];
            #pragma unroll
            for (int rp = 0; rp < MREP; ++rp)
                afrag[rp] = *(const bf16x8*)&feat_bf[(size_t)(rowbase + rp * 16 + m16) * D + ks * 32 + kb];
            #pragma unroll
            for (int nb = 0; nb < 8; ++nb) {
                const bf16x8 bfrag = *(const bf16x8*)&Wt_self[(size_t)(nb * 16 + m16) * D + ks * 32 + kb];
                #pragma unroll
                for (int rp = 0; rp < MREP; ++rp)
                    acc[rp][nb] = __builtin_amdgcn_mfma_f32_16x16x32_bf16(
                        afrag[rp], bfrag, acc[rp][nb], 0, 0, 0);
            }
        }
    }

    __syncthreads();

    if (w < 4) {
        // neigh path: A from swizzled LDS tile
        #pragma unroll
        for (int ks = 0; ks < 4; ++ks) {
            bf16x8 afrag[MREP];
            #pragma unroll
            for (int rp = 0; rp < MREP; ++rp) {
                const int rloc  = rowloc0 + rp * 16 + m16;
                const int cbyte = (ks * 32 + kb) * 2;
                afrag[rp] = *(const bf16x8*)(hsb + rloc * 256 + (cbyte ^ ((rloc & 7) << 4)));
            }
            #pragma unroll
            for (int nb = 0; nb < 8; ++nb) {
                const bf16x8 bfrag = *(const bf16x8*)&Wt_neigh[(size_t)(nb * 16 + m16) * D + ks * 32 + kb];
                #pragma unroll
                for (int rp = 0; rp < MREP; ++rp)
                    acc[rp][nb] = __builtin_amdgcn_mfma_f32_16x16x32_bf16(
                        afrag[rp], bfrag, acc[rp][nb], 0, 0, 0);
            }
        }

        // epilogue
        #pragma unroll
        for (int nb = 0; nb < 8; ++nb) {
            const int col  = nb * 16 + m16;
            const float bias = b_self[col] + b_neigh[col];
            #pragma unroll
            for (int rp = 0; rp < MREP; ++rp) {
                const int orow0 = rowbase + rp * 16 + quad * 4;
                #pragma unroll
                for (int r = 0; r < 4; ++r)
                    out[(size_t)(orow0 + r) * D + col] = acc[rp][nb][r] + bias;
            }
        }
    }
}

// ---------------------------------------------------------------------------
extern "C" void kernel_launch(void* const* d_in, const int* in_sizes, int n_in,
                              void* d_out, int out_size, void* d_ws, size_t ws_size,
                              hipStream_t stream)
{
    const float* feat    = (const float*)d_in[0];
    const float* W_self  = (const float*)d_in[1];
    const float* b_self  = (const float*)d_in[2];
    const float* W_neigh = (const float*)d_in[3];
    const float* b_neigh = (const float*)d_in[4];
    const int*   src_idx = (const int*)d_in[5];
    const int*   dst_idx = (const int*)d_in[6];
    const int n_edges = in_sizes[5];

    // workspace layout
    char* ws = (char*)d_ws;
    __bf16* feat_bf  = (__bf16*)ws;                                  // 32 MB
    int*    row_start = (int*)(feat_bf + (size_t)N_SRC * D);         // 256 KB
    __bf16* Wt_self  = (__bf16*)(row_start + N_DST + 16);
    __bf16* Wt_neigh = Wt_self + D * D;

    const int n_bnd = (n_edges + 255) / 256;
    prep_kernel<<<CONV_BLOCKS + n_bnd + W_BLOCKS, 256, 0, stream>>>(
        feat, dst_idx, n_edges, n_bnd, W_self, W_neigh,
        feat_bf, row_start, Wt_self, Wt_neigh);

    fused_kernel<<<N_DST / MTILE, 512, 0, stream>>>(
        feat_bf, src_idx, row_start, Wt_self, Wt_neigh,
        b_self, b_neigh, (float*)d_out);
}

// Round 5
// 155.309 us; speedup vs baseline: 1.0997x; 1.0180x over previous
//
#include <hip/hip_runtime.h>
#include <hip/hip_bf16.h>

#define N_SRC   131072
#define N_DST   65536
#define D       128      // D_IN == D_OUT == 128

typedef __bf16 bf16x8 __attribute__((ext_vector_type(8)));
typedef float  f32x4  __attribute__((ext_vector_type(4)));

#define CONV_BLOCKS 8192   // (N_SRC*D) / (256 threads * 8 elems) = 8192
#define W_BLOCKS    64     // 64*256 = 16384 = D*D elements

// ---------------------------------------------------------------------------
// Kernel 1 (fused prep): role-split grid.
//  blocks [0, CONV_BLOCKS)                : feat fp32 -> bf16 (streaming)
//  blocks [CONV_BLOCKS, CONV+n_bnd)       : sorted dst -> CSR row_start
//  blocks [CONV+n_bnd, CONV+n_bnd+64)     : W fp32 [k][n] -> Wt bf16 [n][k]
// ---------------------------------------------------------------------------
__global__ __launch_bounds__(256) void prep_kernel(
    const float* __restrict__ feat,
    const int*   __restrict__ dst, int n_edges, int n_bnd_blocks,
    const float* __restrict__ W_self, const float* __restrict__ W_neigh,
    __bf16* __restrict__ feat_bf,
    int*    __restrict__ row_start,
    __bf16* __restrict__ Wt_self, __bf16* __restrict__ Wt_neigh)
{
    const int b = blockIdx.x;
    const int t = threadIdx.x;

    if (b < CONV_BLOCKS) {
        const size_t i0 = ((size_t)b * 256 + t) * 8;
        const float4 a0 = *(const float4*)&feat[i0];
        const float4 a1 = *(const float4*)&feat[i0 + 4];
        bf16x8 o;
        o[0] = (__bf16)a0.x; o[1] = (__bf16)a0.y; o[2] = (__bf16)a0.z; o[3] = (__bf16)a0.w;
        o[4] = (__bf16)a1.x; o[5] = (__bf16)a1.y; o[6] = (__bf16)a1.z; o[7] = (__bf16)a1.w;
        *(bf16x8*)&feat_bf[i0] = o;
    } else if (b < CONV_BLOCKS + n_bnd_blocks) {
        const int e = (b - CONV_BLOCKS) * 256 + t;
        if (e < n_edges) {
            const int d    = dst[e];
            const int prev = (e == 0) ? -1 : dst[e - 1];
            for (int r = prev + 1; r <= d; ++r) row_start[r] = e;
            if (e == n_edges - 1)
                for (int r = d + 1; r <= N_DST; ++r) row_start[r] = n_edges;
        }
    } else {
        const int wb  = b - CONV_BLOCKS - n_bnd_blocks;  // 0..63
        const int idx = wb * 256 + t;                    // 0..16383
        const int k = idx >> 7, n = idx & 127;
        Wt_self [n * D + k] = (__bf16)W_self [k * D + n];
        Wt_neigh[n * D + k] = (__bf16)W_neigh[k * D + n];
    }
}

// ---------------------------------------------------------------------------
// Kernel 2 (fused neigh + dual GEMM). 512 threads, MTILE=128, grid=512.
//
// Round-5 changes vs round 4 (46.1 us; occupancy 20% because phase 2 ran
// on only 4 of 8 waves, and each GEMM wave streamed the whole 32 KB Wt):
//  * COLUMN-SPLIT GEMM across all 8 waves: wave w owns rows (w&3)*32..+31
//    (MREP=2 kept, B-reuse preserved) and output cols (w>>2)*64..+63
//    (nb 0..3). Same MFMA total, 2x waves -> phase-2 time ~halves; per-wave
//    weight traffic halves.
//  * Software-pipelined INDEX fetch in the gather: next 8 clamped src
//    indices loaded before the FMA block (sequential L1-hot loads, not
//    feature gathers -- r3's waste was extra 256B gathers, not idx loads).
//
// Phase 1: gather-mean, 32 groups x 16 lanes, group owns 4 rows; predicated
//   unroll-8, mask-FMA; LDS store XOR-swizzle byte^=(row&7)<<4 (conflict-
//   free ds_read_b128; SQ_LDS_BANK_CONFLICT ~65K verified r1-r4).
// Phase 2: self-GEMM from global (no LDS dep, before barrier -> absorbs
//   gather imbalance), barrier, neigh-GEMM from swizzled LDS.
//   MFMA bf16 16x16x32 layouts (HW-verified):
//     A: lane holds A[m = lane&15][k = (lane>>4)*8 + j]
//     B: lane holds B[k = (lane>>4)*8 + j][n = lane&15]   (from Wt[n][k])
//     C/D: col = lane&15, row = (lane>>4)*4 + reg
// ---------------------------------------------------------------------------
#define MTILE 128
#define MREP  2

__global__ __launch_bounds__(512) void fused_kernel(
    const __bf16* __restrict__ feat_bf,   // bf16 N_SRC x D
    const int*    __restrict__ src,
    const int*    __restrict__ row_start,
    const __bf16* __restrict__ Wt_self,   // bf16 [n][k]
    const __bf16* __restrict__ Wt_neigh,  // bf16 [n][k]
    const float*  __restrict__ b_self,
    const float*  __restrict__ b_neigh,
    float*        __restrict__ out)
{
    __shared__ __align__(16) __bf16 hs[MTILE * D];   // 32 KB, XOR-swizzled rows
    __shared__ int rs[MTILE + 1];
    char* hsb = (char*)hs;

    const int t     = threadIdx.x;
    const int tile0 = blockIdx.x * MTILE;

    // stage CSR bounds for this tile (1 coalesced load, kills per-row trips)
    if (t <= MTILE) rs[t] = row_start[tile0 + t];
    __syncthreads();

    // ---------------- phase 1: gather-mean into LDS ----------------
    {
        const int g    = t >> 4;       // group 0..31
        const int lane = t & 15;
        const int cb   = lane * 16;    // byte offset of this lane's 16B chunk

        #pragma unroll
        for (int rr = 0; rr < MTILE / 32; ++rr) {   // 4 rows per group
            const int rloc = rr * 32 + g;
            const int s0 = rs[rloc];
            const int s1 = rs[rloc + 1];

            float acc[8] = {0.f, 0.f, 0.f, 0.f, 0.f, 0.f, 0.f, 0.f};

            // prefetch first index batch (clamped; idx loads are sequential
            // L1-hot, cheap -- feature gathers below are never padded)
            int idx[8];
            #pragma unroll
            for (int j = 0; j < 8; ++j) {
                int e = s0 + j; e = e < s1 ? e : s1 - 1; e = e > 0 ? e : 0;
                idx[j] = src[e];
            }

            for (int base = s0; base < s1; base += 8) {
                bf16x8 v[8];
                #pragma unroll
                for (int j = 0; j < 8; ++j)
                    v[j] = *(const bf16x8*)((const char*)feat_bf + (size_t)idx[j] * (D * 2) + cb);
                // prefetch next index batch under the gather latency
                int nidx[8];
                #pragma unroll
                for (int j = 0; j < 8; ++j) {
                    int e = base + 8 + j; e = e < s1 ? e : s1 - 1; e = e > 0 ? e : 0;
                    nidx[j] = src[e];
                }
                #pragma unroll
                for (int j = 0; j < 8; ++j) {
                    const float m = (base + j < s1) ? 1.0f : 0.0f;
                    #pragma unroll
                    for (int c = 0; c < 8; ++c)
                        acc[c] = fmaf(m, (float)v[j][c], acc[c]);
                }
                #pragma unroll
                for (int j = 0; j < 8; ++j) idx[j] = nidx[j];
            }

            const float inv = 1.0f / fmaxf((float)(s1 - s0), 1.0f);
            bf16x8 o;
            #pragma unroll
            for (int c = 0; c < 8; ++c) o[c] = (__bf16)(acc[c] * inv);
            // swizzled LDS store (row stride 256 B, chunk XOR by row&7)
            *(bf16x8*)(hsb + rloc * 256 + (cb ^ ((rloc & 7) << 4))) = o;
        }
    }

    // ---------------- phase 2: dual GEMM (all 8 waves, col-split) ----------
    const int w     = t >> 6;         // wave 0..7
    const int l     = t & 63;
    const int m16   = l & 15;
    const int quad  = l >> 4;         // 0..3
    const int kb    = quad * 8;
    const int wrow  = w & 3;          // row-quarter of the tile
    const int whalf = w >> 2;         // column half (0: cols 0-63, 1: 64-127)
    const int rowloc0 = wrow * (16 * MREP);
    const int rowbase = tile0 + rowloc0;
    const int colbase = whalf * 64;

    f32x4 acc[MREP][4];
    #pragma unroll
    for (int rp = 0; rp < MREP; ++rp)
        #pragma unroll
        for (int nb = 0; nb < 4; ++nb)
            acc[rp][nb] = (f32x4){0.f, 0.f, 0.f, 0.f};

    // self path: A straight from global bf16 (no LDS dep -> before barrier)
    #pragma unroll
    for (int ks = 0; ks < 4; ++ks) {
        bf16x8 afrag[MREP];
        #pragma unroll
        for (int rp = 0; rp < MREP; ++rp)
            afrag[rp] = *(const bf16x8*)&feat_bf[(size_t)(rowbase + rp * 16 + m16) * D + ks * 32 + kb];
        #pragma unroll
        for (int nb = 0; nb < 4; ++nb) {
            const bf16x8 bfrag = *(const bf16x8*)&Wt_self[(size_t)(colbase + nb * 16 + m16) * D + ks * 32 + kb];
            #pragma unroll
            for (int rp = 0; rp < MREP; ++rp)
                acc[rp][nb] = __builtin_amdgcn_mfma_f32_16x16x32_bf16(
                    afrag[rp], bfrag, acc[rp][nb], 0, 0, 0);
        }
    }

    __syncthreads();

    // neigh path: A from swizzled LDS tile
    #pragma unroll
    for (int ks = 0; ks < 4; ++ks) {
        bf16x8 afrag[MREP];
        #pragma unroll
        for (int rp = 0; rp < MREP; ++rp) {
            const int rloc  = rowloc0 + rp * 16 + m16;
            const int cbyte = (ks * 32 + kb) * 2;
            afrag[rp] = *(const bf16x8*)(hsb + rloc * 256 + (cbyte ^ ((rloc & 7) << 4)));
        }
        #pragma unroll
        for (int nb = 0; nb < 4; ++nb) {
            const bf16x8 bfrag = *(const bf16x8*)&Wt_neigh[(size_t)(colbase + nb * 16 + m16) * D + ks * 32 + kb];
            #pragma unroll
            for (int rp = 0; rp < MREP; ++rp)
                acc[rp][nb] = __builtin_amdgcn_mfma_f32_16x16x32_bf16(
                    afrag[rp], bfrag, acc[rp][nb], 0, 0, 0);
        }
    }

    // epilogue
    #pragma unroll
    for (int nb = 0; nb < 4; ++nb) {
        const int col  = colbase + nb * 16 + m16;
        const float bias = b_self[col] + b_neigh[col];
        #pragma unroll
        for (int rp = 0; rp < MREP; ++rp) {
            const int orow0 = rowbase + rp * 16 + quad * 4;
            #pragma unroll
            for (int r = 0; r < 4; ++r)
                out[(size_t)(orow0 + r) * D + col] = acc[rp][nb][r] + bias;
        }
    }
}

// ---------------------------------------------------------------------------
extern "C" void kernel_launch(void* const* d_in, const int* in_sizes, int n_in,
                              void* d_out, int out_size, void* d_ws, size_t ws_size,
                              hipStream_t stream)
{
    const float* feat    = (const float*)d_in[0];
    const float* W_self  = (const float*)d_in[1];
    const float* b_self  = (const float*)d_in[2];
    const float* W_neigh = (const float*)d_in[3];
    const float* b_neigh = (const float*)d_in[4];
    const int*   src_idx = (const int*)d_in[5];
    const int*   dst_idx = (const int*)d_in[6];
    const int n_edges = in_sizes[5];

    // workspace layout
    char* ws = (char*)d_ws;
    __bf16* feat_bf  = (__bf16*)ws;                                  // 32 MB
    int*    row_start = (int*)(feat_bf + (size_t)N_SRC * D);         // 256 KB
    __bf16* Wt_self  = (__bf16*)(row_start + N_DST + 16);
    __bf16* Wt_neigh = Wt_self + D * D;

    const int n_bnd = (n_edges + 255) / 256;
    prep_kernel<<<CONV_BLOCKS + n_bnd + W_BLOCKS, 256, 0, stream>>>(
        feat, dst_idx, n_edges, n_bnd, W_self, W_neigh,
        feat_bf, row_start, Wt_self, Wt_neigh);

    fused_kernel<<<N_DST / MTILE, 512, 0, stream>>>(
        feat_bf, src_idx, row_start, Wt_self, Wt_neigh,
        b_self, b_neigh, (float*)d_out);
}